// Round 13
// baseline (275.810 us; speedup 1.0000x reference)
//
#include <hip/hip_runtime.h>
#include <cstdint>
#include <cstddef>

typedef __attribute__((ext_vector_type(8))) __bf16   bf16x8;
typedef __attribute__((ext_vector_type(2))) __bf16   bf16x2;
typedef __attribute__((ext_vector_type(4))) float    f32x4;
typedef __attribute__((ext_vector_type(4))) uint32_t u32x4;

#define N_ROWS   1179648   // 8*384*384
#define N_TILES  73728     // N_ROWS/16
#define TPW      6         // tiles per wave (phase-major)
#define BLOCKS   3072      // 3072 blocks x 4 waves x 6 tiles = 73728
#define SDIM     384
#define VOCAB    5

// LDS map: [0,24576) W1|W2'|W3' bf16 permuted+swizzled; [24576,26624) Wo'^T;
// [26624,27392) b1|b2'|b3' f32; [27392,35072) 4 waves x 6 tiles x 320B out slots
#define WO_OFF   24576
#define BIAS_OFF 26624
#define OUT_OFF  27392

// tanh-form GELU via exp2+rcp: gelu(x) ~= x / (1 + exp2(x*(c1+c2*x^2)))
// |err vs exact| <= ~4e-4 (threshold 7.75e-2)
__device__ __forceinline__ f32x4 gelu4(f32x4 x){
  f32x4 u = x * x;
  f32x4 w = u * (-0.10294456f) + (-2.3021255f);
  f32x4 z = x * w;
  f32x4 e;
  e[0] = __builtin_amdgcn_exp2f(z[0]);
  e[1] = __builtin_amdgcn_exp2f(z[1]);
  e[2] = __builtin_amdgcn_exp2f(z[2]);
  e[3] = __builtin_amdgcn_exp2f(z[3]);
  f32x4 d = e + 1.0f;
  f32x4 r;
  r[0] = __builtin_amdgcn_rcpf(d[0]);
  r[1] = __builtin_amdgcn_rcpf(d[1]);
  r[2] = __builtin_amdgcn_rcpf(d[2]);
  r[3] = __builtin_amdgcn_rcpf(d[3]);
  return x * r;
}

__device__ __forceinline__ bf16x8 mk_bf8(f32x4 a, f32x4 b){
  bf16x8 v;
  v[0]=(__bf16)a[0]; v[1]=(__bf16)a[1]; v[2]=(__bf16)a[2]; v[3]=(__bf16)a[3];
  v[4]=(__bf16)b[0]; v[5]=(__bf16)b[1]; v[6]=(__bf16)b[2]; v[7]=(__bf16)b[3];
  return v;
}

// W-row permutation: global row m -> LDS A-row rho, so acc[mt][r] of lane (h,b)
// is feature 8h + r + 4*(mt&1) + 32*(mt>>1) -> next B frag is pure register repack.
__device__ __forceinline__ int perm_rho(int m){
  return (m & 0x23) | ((m & 4) << 2) | ((m & 0x18) >> 1);
}

__global__ __launch_bounds__(256)
void mlp_kernel(const float* __restrict__ x,
                const float* __restrict__ W1, const float* __restrict__ b1,
                const float* __restrict__ W2, const float* __restrict__ b2,
                const float* __restrict__ W3, const float* __restrict__ b3,
                const float* __restrict__ lng, const float* __restrict__ lnb,
                const float* __restrict__ Wo,  const float* __restrict__ bo,
                float* __restrict__ tmp)
{
  __shared__ __align__(16) uint8_t Wl[35072];

  const int tid  = threadIdx.x;
  const int wav  = tid >> 6, lane = tid & 63;
  const int h    = lane >> 4;
  const int b    = lane & 15;
  const int gw   = blockIdx.x * 4 + wav;
  const int t0   = gw * TPW;

  // ---- 1) issue ALL x loads first: staging below covers their HBM latency ----
  f32x4 xr[TPW][4];
  #pragma unroll
  for (int t8 = 0; t8 < TPW; ++t8) {
    const float* px = x + (size_t)((t0 + t8) * 16 + b) * 64 + 8 * h;
    xr[t8][0] = *(const f32x4*)(px);
    xr[t8][1] = *(const f32x4*)(px + 4);
    xr[t8][2] = *(const f32x4*)(px + 32);
    xr[t8][3] = *(const f32x4*)(px + 36);
  }

  // ---- 2) stage weights with LN-affine folding ----
  {
    int m = tid & 63, g = tid >> 6;
    int rho = perm_rho(m);
    uint8_t* wrow = Wl + rho * 128;
    int swz = (rho & 7) << 4;
    #pragma unroll 1
    for (int idx = g; idx < 96; idx += 4) {   // idx = L*32 + kp
      int L = idx >> 5, kp = idx & 31;
      const float* W = (L == 0) ? W1 : ((L == 1) ? W2 : W3);
      float g0 = (L == 0) ? 1.0f : lng[2 * kp];
      float g1 = (L == 0) ? 1.0f : lng[2 * kp + 1];
      float lo = W[(2 * kp    ) * 64 + m] * g0;
      float hi = W[(2 * kp + 1) * 64 + m] * g1;
      bf16x2 p = { (__bf16)lo, (__bf16)hi };
      *(uint32_t*)(wrow + L * 8192 + ((4 * kp) ^ swz)) = __builtin_bit_cast(uint32_t, p);
    }
    int mm = tid & 15;
    #pragma unroll 1
    for (int kp = tid >> 4; kp < 32; kp += 16) {    // Wo' rows 0..15 (>=5 zero)
      float g0 = lng[2 * kp], g1 = lng[2 * kp + 1];
      float lo = (mm < VOCAB) ? Wo[(2 * kp    ) * VOCAB + mm] * g0 : 0.0f;
      float hi = (mm < VOCAB) ? Wo[(2 * kp + 1) * VOCAB + mm] * g1 : 0.0f;
      bf16x2 p = { (__bf16)lo, (__bf16)hi };
      *(uint32_t*)(Wl + WO_OFF + mm * 128 + ((4 * kp) ^ ((mm & 7) << 4))) =
          __builtin_bit_cast(uint32_t, p);
    }
    // b1 raw; b2' = b2 + W2^T.lnb ; b3' = b3 + W3^T.lnb
    if (tid < 128) {
      int m2 = tid & 63;
      const float* W = (tid < 64) ? W2 : W3;
      float d = (tid < 64) ? b2[m2] : b3[m2];
      #pragma unroll 4
      for (int k = 0; k < 64; ++k) d = __builtin_fmaf(W[k * 64 + m2], lnb[k], d);
      *(float*)(Wl + BIAS_OFF + (64 + tid) * 4) = d;
    } else if (tid < 192) {
      *(float*)(Wl + BIAS_OFF + (tid - 128) * 4) = b1[tid - 128];
    }
  }

  // bo' = bo + Wo^T.lnb (per-lane, overlaps staging latency)
  f32x4 aoInit;
  #pragma unroll
  for (int r = 0; r < 4; ++r) {
    int v = 4 * h + r;
    aoInit[r] = (v < VOCAB) ? bo[v] : 0.0f;
  }
  #pragma unroll 4
  for (int k = 0; k < 64; ++k) {
    float lb = lnb[k];
    #pragma unroll
    for (int r = 0; r < 4; ++r) {
      int v = 4 * h + r;
      if (v < VOCAB) aoInit[r] = __builtin_fmaf(lb, Wo[k * VOCAB + v], aoInit[r]);
    }
  }
  __syncthreads();

  const int swzW = (b & 7) << 4;
  const int rowB = b * 128;
  const int kOff = 16 * h;
  const float* biasL = (const float*)(Wl + BIAS_OFF);

  // ---- 3) pack all tiles' x -> bf16 B fragments (frees xr) ----
  u32x4 bfr[TPW][2];
  #pragma unroll
  for (int t8 = 0; t8 < TPW; ++t8) {
    bfr[t8][0] = __builtin_bit_cast(u32x4, mk_bf8(xr[t8][0], xr[t8][1]));
    bfr[t8][1] = __builtin_bit_cast(u32x4, mk_bf8(xr[t8][2], xr[t8][3]));
  }

  // ---- 4) three layer PHASES: read W/bias once, run 6 independent tile-chains ----
  #pragma unroll
  for (int L = 0; L < 3; ++L) {
    const uint8_t* wp = Wl + L * 8192 + rowB;
    u32x4 w[8];
    f32x4 bini[4];
    #pragma unroll
    for (int mt = 0; mt < 4; ++mt) {
      w[2 * mt]     = *(const u32x4*)(wp + mt * 2048 + ((kOff     ) ^ swzW));
      w[2 * mt + 1] = *(const u32x4*)(wp + mt * 2048 + ((kOff + 64) ^ swzW));
      int base = 8 * h + 4 * (mt & 1) + 32 * (mt >> 1);
      bini[mt] = *(const f32x4*)(biasL + L * 64 + base);
    }

    #pragma unroll
    for (int t8 = 0; t8 < TPW; ++t8) {
      f32x4 acc[4];
      #pragma unroll
      for (int mt = 0; mt < 4; ++mt) {
        acc[mt] = __builtin_amdgcn_mfma_f32_16x16x32_bf16(
            __builtin_bit_cast(bf16x8, w[2 * mt]),
            __builtin_bit_cast(bf16x8, bfr[t8][0]), bini[mt], 0, 0, 0);
        acc[mt] = __builtin_amdgcn_mfma_f32_16x16x32_bf16(
            __builtin_bit_cast(bf16x8, w[2 * mt + 1]),
            __builtin_bit_cast(bf16x8, bfr[t8][1]), acc[mt], 0, 0, 0);
      }

      #pragma unroll
      for (int mt = 0; mt < 4; ++mt) acc[mt] = gelu4(acc[mt]);

      f32x4 vs = acc[0] + acc[1] + acc[2] + acc[3];
      f32x4 vq = acc[0]*acc[0] + acc[1]*acc[1] + acc[2]*acc[2] + acc[3]*acc[3];
      float s1 = (vs[0]+vs[1]) + (vs[2]+vs[3]);
      float s2 = (vq[0]+vq[1]) + (vq[2]+vq[3]);
      s1 += __shfl_xor(s1, 16); s2 += __shfl_xor(s2, 16);
      s1 += __shfl_xor(s1, 32); s2 += __shfl_xor(s2, 32);
      float mu   = s1 * (1.0f/64.0f);
      float var  = __builtin_fmaf(s2, (1.0f/64.0f), -mu * mu);
      float rstd = rsqrtf(var + 1e-5f);
      float nm   = -mu * rstd;

      f32x4 n0 = acc[0] * rstd + nm;
      f32x4 n1 = acc[1] * rstd + nm;
      f32x4 n2 = acc[2] * rstd + nm;
      f32x4 n3 = acc[3] * rstd + nm;
      bfr[t8][0] = __builtin_bit_cast(u32x4, mk_bf8(n0, n1));
      bfr[t8][1] = __builtin_bit_cast(u32x4, mk_bf8(n2, n3));
    }
  }

  // ---- 5) projection phase: Wo' frags once, 6 tiles, per-tile LDS out slots ----
  {
    u32x4 wo0 = *(const u32x4*)(Wl + WO_OFF + rowB + ((kOff     ) ^ swzW));
    u32x4 wo1 = *(const u32x4*)(Wl + WO_OFF + rowB + ((kOff + 64) ^ swzW));
    float* outS = (float*)(Wl + OUT_OFF) + wav * (TPW * 80);

    #pragma unroll
    for (int t8 = 0; t8 < TPW; ++t8) {
      f32x4 ao;
      ao = __builtin_amdgcn_mfma_f32_16x16x32_bf16(
          __builtin_bit_cast(bf16x8, wo0), __builtin_bit_cast(bf16x8, bfr[t8][0]),
          aoInit, 0, 0, 0);
      ao = __builtin_amdgcn_mfma_f32_16x16x32_bf16(
          __builtin_bit_cast(bf16x8, wo1), __builtin_bit_cast(bf16x8, bfr[t8][1]),
          ao, 0, 0, 0);
      float* myF = outS + t8 * 80;
      #pragma unroll
      for (int r = 0; r < 4; ++r) {
        int v = 4 * h + r;
        if (v < VOCAB) myF[b * VOCAB + v] = ao[r];
      }
    }
    #pragma unroll
    for (int t8 = 0; t8 < TPW; ++t8) {
      float* myF = outS + t8 * 80;
      float* dst = tmp + (size_t)(t0 + t8) * 80;
      dst[lane] = myF[lane];
      if (lane < 16) dst[64 + lane] = myF[64 + lane];
    }
  }
}

// symmetrize: out[b,i,j,:] = 0.5*(tmp[b,i,j,:] + tmp[b,j,i,:]), LDS tile transpose
__global__ __launch_bounds__(256)
void sym_kernel(const float* __restrict__ tmp, float* __restrict__ out)
{
  __shared__ float A[32][164];
  __shared__ float B[32][164];
  int bid = blockIdx.x;
  int bb = bid / 144, r2 = bid - bb * 144;
  int ti = r2 / 12,  tj = r2 - ti * 12;
  int i0 = ti * 32,  j0 = tj * 32;
  const size_t base = (size_t)bb * SDIM * SDIM;

  for (int idx = threadIdx.x; idx < 32 * 160; idx += 256) {
    int r = idx / 160, c = idx - r * 160;
    A[r][c] = tmp[(base + (size_t)(i0 + r) * SDIM + j0) * VOCAB + c];
    B[r][c] = tmp[(base + (size_t)(j0 + r) * SDIM + i0) * VOCAB + c];
  }
  __syncthreads();
  for (int idx = threadIdx.x; idx < 32 * 160; idx += 256) {
    int r = idx / 160, c = idx - r * 160;
    int jc = c / 5, v = c - jc * 5;
    out[(base + (size_t)(i0 + r) * SDIM + j0) * VOCAB + c] =
        0.5f * (A[r][c] + B[jc][r * 5 + v]);
  }
}

extern "C" void kernel_launch(void* const* d_in, const int* in_sizes, int n_in,
                              void* d_out, int out_size, void* d_ws, size_t ws_size,
                              hipStream_t stream)
{
  const float* x   = (const float*)d_in[0];
  const float* W1  = (const float*)d_in[1];
  const float* b1  = (const float*)d_in[2];
  const float* W2  = (const float*)d_in[3];
  const float* b2  = (const float*)d_in[4];
  const float* W3  = (const float*)d_in[5];
  const float* b3  = (const float*)d_in[6];
  const float* lng = (const float*)d_in[7];
  const float* lnb = (const float*)d_in[8];
  const float* Wo  = (const float*)d_in[9];
  const float* bo  = (const float*)d_in[10];

  float* tmp = (float*)d_ws;   // 23.6 MB scratch
  float* out = (float*)d_out;

  mlp_kernel<<<BLOCKS, 256, 0, stream>>>(x, W1, b1, W2, b2, W3, b3,
                                         lng, lnb, Wo, bo, tmp);
  sym_kernel<<<8 * 12 * 12, 256, 0, stream>>>(tmp, out);
}

// Round 14
// 147.704 us; speedup vs baseline: 1.8673x; 1.8673x over previous
//
#include <hip/hip_runtime.h>
#include <cstdint>
#include <cstddef>

typedef __attribute__((ext_vector_type(8))) __bf16   bf16x8;
typedef __attribute__((ext_vector_type(2))) __bf16   bf16x2;
typedef __attribute__((ext_vector_type(4))) float    f32x4;
typedef __attribute__((ext_vector_type(4))) uint32_t u32x4;

#define N_ROWS   1179648   // 8*384*384
#define N_TILES  73728     // N_ROWS/16
#define BLOCKS   2048      // 4 waves -> 8192 waves -> 9 tiles/wave
#define TPW      9
#define SDIM     384
#define VOCAB    5

// LDS map (28672 B total -> 5 blocks/CU):
#define WO_OFF   24576
#define BIAS_OFF 26624
#define OUT_OFF  27392     // 4 waves x 320B out-gather

// tanh-form GELU via exp2+rcp on f32x4: gelu(x) ~= x / (1 + exp2(x*(c1+c2*x^2)))
// |err vs exact| <= ~4e-4 (threshold is 7.75e-2)
__device__ __forceinline__ f32x4 gelu4(f32x4 x){
  f32x4 u = x * x;
  f32x4 w = u * (-0.10294456f) + (-2.3021255f);
  f32x4 z = x * w;
  f32x4 e;
  e[0] = __builtin_amdgcn_exp2f(z[0]);
  e[1] = __builtin_amdgcn_exp2f(z[1]);
  e[2] = __builtin_amdgcn_exp2f(z[2]);
  e[3] = __builtin_amdgcn_exp2f(z[3]);
  f32x4 d = e + 1.0f;
  f32x4 r;
  r[0] = __builtin_amdgcn_rcpf(d[0]);
  r[1] = __builtin_amdgcn_rcpf(d[1]);
  r[2] = __builtin_amdgcn_rcpf(d[2]);
  r[3] = __builtin_amdgcn_rcpf(d[3]);
  return x * r;
}

__device__ __forceinline__ bf16x8 mk_bf8(f32x4 a, f32x4 b){
  bf16x8 v;
  v[0]=(__bf16)a[0]; v[1]=(__bf16)a[1]; v[2]=(__bf16)a[2]; v[3]=(__bf16)a[3];
  v[4]=(__bf16)b[0]; v[5]=(__bf16)b[1]; v[6]=(__bf16)b[2]; v[7]=(__bf16)b[3];
  return v;
}

// W-row permutation: global row m -> LDS A-row rho, so that acc[mt][r] of lane
// (h,b) equals feature 8h + r + 4*(mt&1) + 32*(mt>>1). Then the next layer's
// B fragment is a pure in-register repack (no LDS bounce, no cross-lane).
__device__ __forceinline__ int perm_rho(int m){
  return (m & 0x23) | ((m & 4) << 2) | ((m & 0x18) >> 1);
}

__global__ __launch_bounds__(256)
void mlp_kernel(const float* __restrict__ x,
                const float* __restrict__ W1, const float* __restrict__ b1,
                const float* __restrict__ W2, const float* __restrict__ b2,
                const float* __restrict__ W3, const float* __restrict__ b3,
                const float* __restrict__ lng, const float* __restrict__ lnb,
                const float* __restrict__ Wo,  const float* __restrict__ bo,
                float* __restrict__ tmp)
{
  __shared__ __align__(16) uint8_t Wl[28672];

  const int tid = threadIdx.x;

  // ---- stage: W1..W3 fp32 -> LDS bf16, permuted rows, swizzle byte^=((rho&7)<<4) ----
  {
    int m = tid & 63, g = tid >> 6;
    int rho = perm_rho(m);
    uint8_t* wrow = Wl + rho * 128;
    int swz = (rho & 7) << 4;
    #pragma unroll 1
    for (int idx = g; idx < 96; idx += 4) {   // idx = L*32 + kp
      int L = idx >> 5, kp = idx & 31;
      const float* W = (L == 0) ? W1 : ((L == 1) ? W2 : W3);
      float lo = W[(2 * kp    ) * 64 + m];
      float hi = W[(2 * kp + 1) * 64 + m];
      bf16x2 p = { (__bf16)lo, (__bf16)hi };
      *(uint32_t*)(wrow + L * 8192 + ((4 * kp) ^ swz)) = __builtin_bit_cast(uint32_t, p);
    }
    int mm = tid & 15;
    #pragma unroll 1
    for (int kp = tid >> 4; kp < 32; kp += 16) {    // Wo^T rows 0..15 natural (>=5 zero)
      float lo = (mm < VOCAB) ? Wo[(2 * kp    ) * VOCAB + mm] : 0.0f;
      float hi = (mm < VOCAB) ? Wo[(2 * kp + 1) * VOCAB + mm] : 0.0f;
      bf16x2 p = { (__bf16)lo, (__bf16)hi };
      *(uint32_t*)(Wl + WO_OFF + mm * 128 + ((4 * kp) ^ ((mm & 7) << 4))) =
          __builtin_bit_cast(uint32_t, p);
    }
    if (tid < 192) {                                 // biases -> LDS f32 (natural order)
      float v = (tid < 64) ? b1[tid] : ((tid < 128) ? b2[tid - 64] : b3[tid - 128]);
      *(float*)(Wl + BIAS_OFF + tid * 4) = v;
    }
  }
  __syncthreads();

  const int wav  = tid >> 6, lane = tid & 63;
  const int h    = lane >> 4;            // k sub-block selector
  const int b    = lane & 15;            // batch-row in tile / A-row p
  const int swzW = (b & 7) << 4;
  const int rowB = b * 128;
  const int kOff = 16 * h;
  const float* biasL = (const float*)(Wl + BIAS_OFF);
  float* myF = (float*)(Wl + OUT_OFF) + wav * 80;

  // per-lane feature bases for the 4 acc sets (permuted layout)
  // base(mt) = 8h + 4*(mt&1) + 32*(mt>>1)
  f32x4 ggr[4], bbr[4], aoInit;
  #pragma unroll
  for (int mt = 0; mt < 4; ++mt) {
    int base = 8 * h + 4 * (mt & 1) + 32 * (mt >> 1);
    ggr[mt] = *(const f32x4*)(lng + base);
    bbr[mt] = *(const f32x4*)(lnb + base);
  }
  #pragma unroll
  for (int r = 0; r < 4; ++r) {
    int v = 4 * h + r;
    aoInit[r] = (v < VOCAB) ? bo[v] : 0.0f;
  }

  const int gw = blockIdx.x * 4 + wav;   // 0..8191
  int t = gw * TPW;

  // prime x prefetch (tile t): feats 8h..8h+7 and 32+8h..+7 of row b
  f32x4 xn[4];
  {
    const float* px = x + (size_t)(t * 16 + b) * 64 + 8 * h;
    xn[0] = *(const f32x4*)(px);      xn[1] = *(const f32x4*)(px + 4);
    xn[2] = *(const f32x4*)(px + 32); xn[3] = *(const f32x4*)(px + 36);
  }

  #pragma unroll 1
  for (int i = 0; i < TPW; ++i, ++t) {
    u32x4 bfr[2];
    bfr[0] = __builtin_bit_cast(u32x4, mk_bf8(xn[0], xn[1]));
    bfr[1] = __builtin_bit_cast(u32x4, mk_bf8(xn[2], xn[3]));

    { // prefetch next tile's x (hidden under this tile's compute)
      int tn = (i + 1 < TPW) ? (t + 1) : t;
      const float* pn = x + (size_t)(tn * 16 + b) * 64 + 8 * h;
      xn[0] = *(const f32x4*)(pn);      xn[1] = *(const f32x4*)(pn + 4);
      xn[2] = *(const f32x4*)(pn + 32); xn[3] = *(const f32x4*)(pn + 36);
    }

    // ---- three (Linear -> gelu -> LN) blocks, zero inter-layer LDS ----
    #pragma unroll
    for (int L = 0; L < 3; ++L) {
      const uint8_t* wp = Wl + L * 8192 + rowB;
      f32x4 acc[4];
      #pragma unroll
      for (int mt = 0; mt < 4; ++mt) {
        u32x4 w0 = *(const u32x4*)(wp + mt * 2048 + ((kOff     ) ^ swzW));
        u32x4 w1 = *(const u32x4*)(wp + mt * 2048 + ((kOff + 64) ^ swzW));
        int base = 8 * h + 4 * (mt & 1) + 32 * (mt >> 1);
        acc[mt] = *(const f32x4*)(biasL + L * 64 + base);
        acc[mt] = __builtin_amdgcn_mfma_f32_16x16x32_bf16(
            __builtin_bit_cast(bf16x8, w0), __builtin_bit_cast(bf16x8, bfr[0]), acc[mt], 0, 0, 0);
        acc[mt] = __builtin_amdgcn_mfma_f32_16x16x32_bf16(
            __builtin_bit_cast(bf16x8, w1), __builtin_bit_cast(bf16x8, bfr[1]), acc[mt], 0, 0, 0);
      }

      #pragma unroll
      for (int mt = 0; mt < 4; ++mt) acc[mt] = gelu4(acc[mt]);

      // LayerNorm stats over row b (partition across lanes b, b+16, b+32, b+48)
      f32x4 vs = acc[0] + acc[1] + acc[2] + acc[3];
      f32x4 vq = acc[0]*acc[0] + acc[1]*acc[1] + acc[2]*acc[2] + acc[3]*acc[3];
      float s1 = (vs[0]+vs[1]) + (vs[2]+vs[3]);
      float s2 = (vq[0]+vq[1]) + (vq[2]+vq[3]);
      s1 += __shfl_xor(s1, 16); s2 += __shfl_xor(s2, 16);
      s1 += __shfl_xor(s1, 32); s2 += __shfl_xor(s2, 32);
      float mu   = s1 * (1.0f/64.0f);
      float var  = __builtin_fmaf(s2, (1.0f/64.0f), -mu * mu);
      float rstd = rsqrtf(var + 1e-5f);
      float nm   = -mu * rstd;

      // normalize + affine, then PURE-REGISTER repack into next B fragments:
      // acc[0]|acc[1] -> feats 8h..8h+7 ; acc[2]|acc[3] -> feats 32+8h..+7
      f32x4 n0 = (acc[0] * rstd + nm) * ggr[0] + bbr[0];
      f32x4 n1 = (acc[1] * rstd + nm) * ggr[1] + bbr[1];
      f32x4 n2 = (acc[2] * rstd + nm) * ggr[2] + bbr[2];
      f32x4 n3 = (acc[3] * rstd + nm) * ggr[3] + bbr[3];
      bfr[0] = __builtin_bit_cast(u32x4, mk_bf8(n0, n1));
      bfr[1] = __builtin_bit_cast(u32x4, mk_bf8(n2, n3));
    }

    // ---- output projection out^T = Wo^T . h3^T + bo (natural m order) ----
    f32x4 ao = aoInit;
    {
      const uint8_t* wp = Wl + WO_OFF + rowB;
      u32x4 w0 = *(const u32x4*)(wp + ((kOff     ) ^ swzW));
      u32x4 w1 = *(const u32x4*)(wp + ((kOff + 64) ^ swzW));
      ao = __builtin_amdgcn_mfma_f32_16x16x32_bf16(
          __builtin_bit_cast(bf16x8, w0), __builtin_bit_cast(bf16x8, bfr[0]), ao, 0, 0, 0);
      ao = __builtin_amdgcn_mfma_f32_16x16x32_bf16(
          __builtin_bit_cast(bf16x8, w1), __builtin_bit_cast(bf16x8, bfr[1]), ao, 0, 0, 0);
    }

    // gather 16x5 floats in per-wave LDS slot, store 320B coalesced
    #pragma unroll
    for (int r = 0; r < 4; ++r) {
      int v = 4 * h + r;
      if (v < VOCAB) myF[b * VOCAB + v] = ao[r];
    }
    float* dst = tmp + (size_t)t * 80;
    dst[lane] = myF[lane];
    if (lane < 16) dst[64 + lane] = myF[64 + lane];
  }
}

// symmetrize: out[b,i,j,:] = 0.5*(tmp[b,i,j,:] + tmp[b,j,i,:]), LDS tile transpose
__global__ __launch_bounds__(256)
void sym_kernel(const float* __restrict__ tmp, float* __restrict__ out)
{
  __shared__ float A[32][164];
  __shared__ float B[32][164];
  int bid = blockIdx.x;
  int bb = bid / 144, r2 = bid - bb * 144;
  int ti = r2 / 12,  tj = r2 - ti * 12;
  int i0 = ti * 32,  j0 = tj * 32;
  const size_t base = (size_t)bb * SDIM * SDIM;

  for (int idx = threadIdx.x; idx < 32 * 160; idx += 256) {
    int r = idx / 160, c = idx - r * 160;
    A[r][c] = tmp[(base + (size_t)(i0 + r) * SDIM + j0) * VOCAB + c];
    B[r][c] = tmp[(base + (size_t)(j0 + r) * SDIM + i0) * VOCAB + c];
  }
  __syncthreads();
  for (int idx = threadIdx.x; idx < 32 * 160; idx += 256) {
    int r = idx / 160, c = idx - r * 160;
    int jc = c / 5, v = c - jc * 5;
    out[(base + (size_t)(i0 + r) * SDIM + j0) * VOCAB + c] =
        0.5f * (A[r][c] + B[jc][r * 5 + v]);
  }
}

extern "C" void kernel_launch(void* const* d_in, const int* in_sizes, int n_in,
                              void* d_out, int out_size, void* d_ws, size_t ws_size,
                              hipStream_t stream)
{
  const float* x   = (const float*)d_in[0];
  const float* W1  = (const float*)d_in[1];
  const float* b1  = (const float*)d_in[2];
  const float* W2  = (const float*)d_in[3];
  const float* b2  = (const float*)d_in[4];
  const float* W3  = (const float*)d_in[5];
  const float* b3  = (const float*)d_in[6];
  const float* lng = (const float*)d_in[7];
  const float* lnb = (const float*)d_in[8];
  const float* Wo  = (const float*)d_in[9];
  const float* bo  = (const float*)d_in[10];

  float* tmp = (float*)d_ws;   // 23.6 MB scratch
  float* out = (float*)d_out;

  mlp_kernel<<<BLOCKS, 256, 0, stream>>>(x, W1, b1, W2, b2, W3, b3,
                                         lng, lnb, Wo, bo, tmp);
  sym_kernel<<<8 * 12 * 12, 256, 0, stream>>>(tmp, out);
}

// Round 15
// 136.480 us; speedup vs baseline: 2.0209x; 1.0822x over previous
//
#include <hip/hip_runtime.h>
#include <cstdint>
#include <cstddef>

typedef __attribute__((ext_vector_type(8))) __bf16   bf16x8;
typedef __attribute__((ext_vector_type(2))) __bf16   bf16x2;
typedef __attribute__((ext_vector_type(4))) float    f32x4;
typedef __attribute__((ext_vector_type(4))) uint32_t u32x4;

#define SDIM     384
#define VOCAB    5
#define SPW      8          // strips (16-position tiles) per wave
#define WGPB     288        // workgroups per batch: 276 off-diag pairs + 12 diag-pair wgs
#define BLOCKS   (8 * WGPB) // 2304

// LDS map (37632 B): [0,24576) W1|W2|W3 bf16 permuted+swizzled;
// [24576,26624) Wo^T padded; [26624,27392) b1|b2|b3 f32;
// [27392,37632) out stash: 2 blocks x 16 strips x 80 f32
#define WO_OFF   24576
#define BIAS_OFF 26624
#define OUT_OFF  27392

// tanh-form GELU via exp2+rcp on f32x4: gelu(x) ~= x / (1 + exp2(x*(c1+c2*x^2)))
// |err vs exact| <= ~4e-4 (threshold is 7.75e-2)
__device__ __forceinline__ f32x4 gelu4(f32x4 x){
  f32x4 u = x * x;
  f32x4 w = u * (-0.10294456f) + (-2.3021255f);
  f32x4 z = x * w;
  f32x4 e;
  e[0] = __builtin_amdgcn_exp2f(z[0]);
  e[1] = __builtin_amdgcn_exp2f(z[1]);
  e[2] = __builtin_amdgcn_exp2f(z[2]);
  e[3] = __builtin_amdgcn_exp2f(z[3]);
  f32x4 d = e + 1.0f;
  f32x4 r;
  r[0] = __builtin_amdgcn_rcpf(d[0]);
  r[1] = __builtin_amdgcn_rcpf(d[1]);
  r[2] = __builtin_amdgcn_rcpf(d[2]);
  r[3] = __builtin_amdgcn_rcpf(d[3]);
  return x * r;
}

__device__ __forceinline__ bf16x8 mk_bf8(f32x4 a, f32x4 b){
  bf16x8 v;
  v[0]=(__bf16)a[0]; v[1]=(__bf16)a[1]; v[2]=(__bf16)a[2]; v[3]=(__bf16)a[3];
  v[4]=(__bf16)b[0]; v[5]=(__bf16)b[1]; v[6]=(__bf16)b[2]; v[7]=(__bf16)b[3];
  return v;
}

// W-row permutation: global row m -> LDS A-row rho, so that acc[mt][r] of lane
// (h,b) equals feature 8h + r + 4*(mt&1) + 32*(mt>>1). Then the next layer's
// B fragment is a pure in-register repack (no LDS bounce, no cross-lane).
__device__ __forceinline__ int perm_rho(int m){
  return (m & 0x23) | ((m & 4) << 2) | ((m & 0x18) >> 1);
}

__global__ __launch_bounds__(256)
void mlp_sym_kernel(const float* __restrict__ x,
                    const float* __restrict__ W1, const float* __restrict__ b1,
                    const float* __restrict__ W2, const float* __restrict__ b2,
                    const float* __restrict__ W3, const float* __restrict__ b3,
                    const float* __restrict__ lng, const float* __restrict__ lnb,
                    const float* __restrict__ Wo,  const float* __restrict__ bo,
                    float* __restrict__ out)
{
  __shared__ __align__(16) uint8_t Wl[37632];

  const int tid = threadIdx.x;

  // ---- stage: W1..W3 fp32 -> LDS bf16, permuted rows, swizzle byte^=((rho&7)<<4) ----
  {
    int m = tid & 63, g = tid >> 6;
    int rho = perm_rho(m);
    uint8_t* wrow = Wl + rho * 128;
    int swz = (rho & 7) << 4;
    #pragma unroll 1
    for (int idx = g; idx < 96; idx += 4) {   // idx = L*32 + kp
      int L = idx >> 5, kp = idx & 31;
      const float* W = (L == 0) ? W1 : ((L == 1) ? W2 : W3);
      float lo = W[(2 * kp    ) * 64 + m];
      float hi = W[(2 * kp + 1) * 64 + m];
      bf16x2 p = { (__bf16)lo, (__bf16)hi };
      *(uint32_t*)(wrow + L * 8192 + ((4 * kp) ^ swz)) = __builtin_bit_cast(uint32_t, p);
    }
    int mm = tid & 15;
    #pragma unroll 1
    for (int kp = tid >> 4; kp < 32; kp += 16) {    // Wo^T rows 0..15 natural (>=5 zero)
      float lo = (mm < VOCAB) ? Wo[(2 * kp    ) * VOCAB + mm] : 0.0f;
      float hi = (mm < VOCAB) ? Wo[(2 * kp + 1) * VOCAB + mm] : 0.0f;
      bf16x2 p = { (__bf16)lo, (__bf16)hi };
      *(uint32_t*)(Wl + WO_OFF + mm * 128 + ((4 * kp) ^ ((mm & 7) << 4))) =
          __builtin_bit_cast(uint32_t, p);
    }
    if (tid < 192) {                                 // biases -> LDS f32 (natural order)
      float v = (tid < 64) ? b1[tid] : ((tid < 128) ? b2[tid - 64] : b3[tid - 128]);
      *(float*)(Wl + BIAS_OFF + tid * 4) = v;
    }
  }
  __syncthreads();

  // ---- decode workgroup -> block pair {(I,J),(J,I)} or two diagonal blocks ----
  const int bb  = blockIdx.x / WGPB;
  const int rem = blockIdx.x - bb * WGPB;
  int I0, J0, I1, J1;
  bool diag;
  if (rem < 276) {            // off-diagonal unordered pair, I < J (24x24 block grid)
    int I = 0, acc = 0;
    while (acc + (23 - I) <= rem) { acc += 23 - I; ++I; }
    int J = I + 1 + (rem - acc);
    I0 = I << 4; J0 = J << 4; I1 = J << 4; J1 = I << 4; diag = false;
  } else {                    // two diagonal blocks
    int d = rem - 276;        // 0..11
    I0 = J0 = (2 * d) << 4; I1 = J1 = (2 * d + 1) << 4; diag = true;
  }

  const int wav  = tid >> 6, lane = tid & 63;
  const int h    = lane >> 4;            // k sub-block selector
  const int b    = lane & 15;            // position within strip
  const int swzW = (b & 7) << 4;
  const int rowB = b * 128;
  const int kOff = 16 * h;
  const float* biasL = (const float*)(Wl + BIAS_OFF);
  float* outS = (float*)(Wl + OUT_OFF);  // 2x1280 f32 stash

  const int blk  = wav >> 1, half = wav & 1;   // wave -> (block, strip-half)
  const int rowb = (blk ? I1 : I0) + 8 * half;
  const int colb = (blk ? J1 : J0);
  const long base0 = ((long)(bb * SDIM + rowb)) * SDIM + colb;  // position index

  // per-lane feature bases for the 4 acc sets (permuted layout)
  f32x4 ggr[4], bbr[4], aoInit;
  #pragma unroll
  for (int mt = 0; mt < 4; ++mt) {
    int base = 8 * h + 4 * (mt & 1) + 32 * (mt >> 1);
    ggr[mt] = *(const f32x4*)(lng + base);
    bbr[mt] = *(const f32x4*)(lnb + base);
  }
  #pragma unroll
  for (int r = 0; r < 4; ++r) {
    int v = 4 * h + r;
    aoInit[r] = (v < VOCAB) ? bo[v] : 0.0f;
  }

  // prime x prefetch (strip 0)
  f32x4 xn[4];
  {
    const float* px = x + (size_t)(base0 + b) * 64 + 8 * h;
    xn[0] = *(const f32x4*)(px);      xn[1] = *(const f32x4*)(px + 4);
    xn[2] = *(const f32x4*)(px + 32); xn[3] = *(const f32x4*)(px + 36);
  }

  #pragma unroll 1
  for (int i = 0; i < SPW; ++i) {
    u32x4 bfr[2];
    bfr[0] = __builtin_bit_cast(u32x4, mk_bf8(xn[0], xn[1]));
    bfr[1] = __builtin_bit_cast(u32x4, mk_bf8(xn[2], xn[3]));

    { // prefetch next strip's x (stride 384 positions; hidden under compute)
      int inext = (i + 1 < SPW) ? (i + 1) : i;
      const float* pn = x + (size_t)(base0 + inext * SDIM + b) * 64 + 8 * h;
      xn[0] = *(const f32x4*)(pn);      xn[1] = *(const f32x4*)(pn + 4);
      xn[2] = *(const f32x4*)(pn + 32); xn[3] = *(const f32x4*)(pn + 36);
    }

    // ---- three (Linear -> gelu -> LN) blocks, zero inter-layer LDS ----
    #pragma unroll
    for (int L = 0; L < 3; ++L) {
      const uint8_t* wp = Wl + L * 8192 + rowB;
      f32x4 acc[4];
      #pragma unroll
      for (int mt = 0; mt < 4; ++mt) {
        u32x4 w0 = *(const u32x4*)(wp + mt * 2048 + ((kOff     ) ^ swzW));
        u32x4 w1 = *(const u32x4*)(wp + mt * 2048 + ((kOff + 64) ^ swzW));
        int base = 8 * h + 4 * (mt & 1) + 32 * (mt >> 1);
        acc[mt] = *(const f32x4*)(biasL + L * 64 + base);
        acc[mt] = __builtin_amdgcn_mfma_f32_16x16x32_bf16(
            __builtin_bit_cast(bf16x8, w0), __builtin_bit_cast(bf16x8, bfr[0]), acc[mt], 0, 0, 0);
        acc[mt] = __builtin_amdgcn_mfma_f32_16x16x32_bf16(
            __builtin_bit_cast(bf16x8, w1), __builtin_bit_cast(bf16x8, bfr[1]), acc[mt], 0, 0, 0);
      }

      #pragma unroll
      for (int mt = 0; mt < 4; ++mt) acc[mt] = gelu4(acc[mt]);

      // LayerNorm stats over the strip position (lanes b, b+16, b+32, b+48)
      f32x4 vs = acc[0] + acc[1] + acc[2] + acc[3];
      f32x4 vq = acc[0]*acc[0] + acc[1]*acc[1] + acc[2]*acc[2] + acc[3]*acc[3];
      float s1 = (vs[0]+vs[1]) + (vs[2]+vs[3]);
      float s2 = (vq[0]+vq[1]) + (vq[2]+vq[3]);
      s1 += __shfl_xor(s1, 16); s2 += __shfl_xor(s2, 16);
      s1 += __shfl_xor(s1, 32); s2 += __shfl_xor(s2, 32);
      float mu   = s1 * (1.0f/64.0f);
      float var  = __builtin_fmaf(s2, (1.0f/64.0f), -mu * mu);
      float rstd = rsqrtf(var + 1e-5f);
      float nm   = -mu * rstd;

      // normalize + affine, then PURE-REGISTER repack into next B fragments
      f32x4 n0 = (acc[0] * rstd + nm) * ggr[0] + bbr[0];
      f32x4 n1 = (acc[1] * rstd + nm) * ggr[1] + bbr[1];
      f32x4 n2 = (acc[2] * rstd + nm) * ggr[2] + bbr[2];
      f32x4 n3 = (acc[3] * rstd + nm) * ggr[3] + bbr[3];
      bfr[0] = __builtin_bit_cast(u32x4, mk_bf8(n0, n1));
      bfr[1] = __builtin_bit_cast(u32x4, mk_bf8(n2, n3));
    }

    // ---- output projection out^T = Wo^T . h3^T + bo ----
    f32x4 ao = aoInit;
    {
      const uint8_t* wp = Wl + WO_OFF + rowB;
      u32x4 w0 = *(const u32x4*)(wp + ((kOff     ) ^ swzW));
      u32x4 w1 = *(const u32x4*)(wp + ((kOff + 64) ^ swzW));
      ao = __builtin_amdgcn_mfma_f32_16x16x32_bf16(
          __builtin_bit_cast(bf16x8, w0), __builtin_bit_cast(bf16x8, bfr[0]), ao, 0, 0, 0);
      ao = __builtin_amdgcn_mfma_f32_16x16x32_bf16(
          __builtin_bit_cast(bf16x8, w1), __builtin_bit_cast(bf16x8, bfr[1]), ao, 0, 0, 0);
    }

    // stash 16x5 floats into this strip's LDS slot (no global store in loop)
    float* myF = outS + blk * 1280 + (8 * half + i) * 80;
    #pragma unroll
    for (int r = 0; r < 4; ++r) {
      int v = 4 * h + r;
      if (v < VOCAB) myF[b * VOCAB + v] = ao[r];
    }
  }
  __syncthreads();

  // ---- fused symmetrization epilogue: out = 0.5*(blk + partner^T), coalesced ----
  #pragma unroll 1
  for (int idx = tid; idx < 2560; idx += 256) {
    int bk = (idx >= 1280) ? 1 : 0;
    int q2 = idx - bk * 1280;
    int r  = q2 / 80;
    int q  = q2 - r * 80;
    int c  = q / 5;
    int v  = q - c * 5;
    int pb = diag ? bk : 1 - bk;
    float val = 0.5f * (outS[bk * 1280 + r * 80 + q] +
                        outS[pb * 1280 + c * 80 + r * 5 + v]);
    int ii = (bk ? I1 : I0) + r;
    int jj = (bk ? J1 : J0) + c;
    out[((size_t)(bb * SDIM + ii) * SDIM + jj) * VOCAB + v] = val;
  }
}

extern "C" void kernel_launch(void* const* d_in, const int* in_sizes, int n_in,
                              void* d_out, int out_size, void* d_ws, size_t ws_size,
                              hipStream_t stream)
{
  const float* x   = (const float*)d_in[0];
  const float* W1  = (const float*)d_in[1];
  const float* b1  = (const float*)d_in[2];
  const float* W2  = (const float*)d_in[3];
  const float* b2  = (const float*)d_in[4];
  const float* W3  = (const float*)d_in[5];
  const float* b3  = (const float*)d_in[6];
  const float* lng = (const float*)d_in[7];
  const float* lnb = (const float*)d_in[8];
  const float* Wo  = (const float*)d_in[9];
  const float* bo  = (const float*)d_in[10];

  float* out = (float*)d_out;

  mlp_sym_kernel<<<BLOCKS, 256, 0, stream>>>(x, W1, b1, W2, b2, W3, b3,
                                             lng, lnb, Wo, bo, out);
}